// Round 2
// baseline (2070.768 us; speedup 1.0000x reference)
//
#include <hip/hip_runtime.h>
#include <cstdint>

#define E 4096
#define SEQL 4096
#define NH 16
#define HD 256

typedef unsigned short u16;
typedef unsigned int u32;
typedef __attribute__((ext_vector_type(8))) short bf16x8;
typedef __attribute__((ext_vector_type(4))) float f32x4;

__device__ __forceinline__ u16 f2bf(float f) {
  union { float f; u32 u; } x; x.f = f;
  u32 r = x.u + 0x7FFFu + ((x.u >> 16) & 1u);
  return (u16)(r >> 16);
}
__device__ __forceinline__ float bf2f(u16 b) {
  union { u32 u; float f; } x; x.u = ((u32)b) << 16; return x.f;
}

__device__ __forceinline__ void gload_lds16(const void* g, void* l) {
  __builtin_amdgcn_global_load_lds((const __attribute__((address_space(1))) void*)g,
                                   (__attribute__((address_space(3))) void*)l, 16, 0, 0);
}

// ---------------- fp32 -> bf16 cast (vectorized) ----------------
__global__ __launch_bounds__(256) void cast_kernel(const float4* __restrict__ in,
                                                   ushort4* __restrict__ out, int n4) {
  int i = blockIdx.x * 256 + threadIdx.x;
  if (i < n4) {
    float4 v = in[i];
    ushort4 o;
    o.x = f2bf(v.x); o.y = f2bf(v.y); o.z = f2bf(v.z); o.w = f2bf(v.w);
    out[i] = o;
  }
}

// ---------------- sin/cos table ----------------
__global__ __launch_bounds__(256) void sincos_kernel(float2* __restrict__ sc) {
  int i = blockIdx.x * 256 + threadIdx.x;
  if (i < SEQL * 32) {
    int s = i >> 5, p = i & 31;
    float inv = powf(10000.0f, -(float)p * (1.0f / 32.0f));
    float a = (float)s * inv;
    sc[i] = make_float2(sinf(a), cosf(a));
  }
}

// ---------------- RoPE (GPT-J rotate-every-two) ----------------
__global__ __launch_bounds__(256) void rope_kernel(u16* __restrict__ q, u16* __restrict__ k,
                                                   const float2* __restrict__ sc) {
  int i = blockIdx.x * 256 + threadIdx.x;
  if (i >= SEQL * NH * 32) return;
  int p = i & 31, h = (i >> 5) & 15, s = i >> 9;
  float2 cs = sc[(s << 5) | p];
  size_t off = ((size_t)s << 12) + ((size_t)h << 8) + ((size_t)p << 1);
  {
    u32* qp = (u32*)(q + off);
    u32 raw = *qp;
    float x0 = bf2f((u16)(raw & 0xFFFFu));
    float x1 = bf2f((u16)(raw >> 16));
    float o0 = x0 * cs.y - x1 * cs.x;
    float o1 = x1 * cs.y + x0 * cs.x;
    *qp = (u32)f2bf(o0) | ((u32)f2bf(o1) << 16);
  }
  {
    u32* kp = (u32*)(k + off);
    u32 raw = *kp;
    float x0 = bf2f((u16)(raw & 0xFFFFu));
    float x1 = bf2f((u16)(raw >> 16));
    float o0 = x0 * cs.y - x1 * cs.x;
    float o1 = x1 * cs.y + x0 * cs.x;
    *kp = (u32)f2bf(o0) | ((u32)f2bf(o1) << 16);
  }
}

// ---------------- bf16 GEMM, C[i][j] = sum_k A[i][k]*B[j][k] ----------------
// TRANSOUT: write C^T (element (r,c) -> Cp[c*M + r]) as bf16 (for V -> Vt global).
template <bool BF16OUT, bool TRANSOUT>
__global__ __launch_bounds__(256) void gemm_bt(const u16* __restrict__ A, const u16* __restrict__ B,
                                               void* __restrict__ Cp, int M, int N, int K) {
  __shared__ u16 As[2][128 * 32];
  __shared__ u16 Bs[2][128 * 32];
  const int tid = threadIdx.x, w = tid >> 6, lane = tid & 63;
  const int c15 = lane & 15, q4 = lane >> 4;

  int bid = blockIdx.x;
  int cpx = gridDim.x >> 3;
  int sw = (bid & 7) * cpx + (bid >> 3);
  const int mt = M >> 7;
  const int bm = sw & (mt - 1), bn = sw / mt;
  const int row0 = bm << 7, col0 = bn << 7;
  const int wr = w >> 1, wc = w & 1;

  f32x4 acc[4][4] = {};

  auto stage = [&](int buf, int k0) {
#pragma unroll
    for (int i = 0; i < 2; ++i) {
      int p = w * 128 + i * 64 + lane;
      int r = p >> 2, cph = p & 3;
      int gl = cph ^ ((r >> 1) & 3);
      gload_lds16(A + (size_t)(row0 + r) * K + k0 + gl * 8, &As[buf][(w * 128 + i * 64) * 8]);
      gload_lds16(B + (size_t)(col0 + r) * K + k0 + gl * 8, &Bs[buf][(w * 128 + i * 64) * 8]);
    }
  };

  stage(0, 0);
  const int nt = K >> 5;
  for (int t = 0; t < nt; ++t) {
    const int cur = t & 1;
    __syncthreads();
    if (t + 1 < nt) stage(cur ^ 1, (t + 1) << 5);
    bf16x8 af[4], bfr[4];
#pragma unroll
    for (int m = 0; m < 4; ++m) {
      int ra = wr * 64 + m * 16 + c15;
      int pga = q4 ^ ((ra >> 1) & 3);
      af[m] = *(const bf16x8*)&As[cur][ra * 32 + pga * 8];
      int rb = wc * 64 + m * 16 + c15;
      int pgb = q4 ^ ((rb >> 1) & 3);
      bfr[m] = *(const bf16x8*)&Bs[cur][rb * 32 + pgb * 8];
    }
#pragma unroll
    for (int m = 0; m < 4; ++m)
#pragma unroll
      for (int n = 0; n < 4; ++n)
        acc[m][n] = __builtin_amdgcn_mfma_f32_16x16x32_bf16(af[m], bfr[n], acc[m][n], 0, 0, 0);
  }

#pragma unroll
  for (int m = 0; m < 4; ++m) {
#pragma unroll
    for (int n = 0; n < 4; ++n) {
      if constexpr (TRANSOUT) {
        int r0 = row0 + wr * 64 + m * 16 + q4 * 4;
        int c = col0 + wc * 64 + n * 16 + c15;
        u32 lo = (u32)f2bf(acc[m][n][0]) | ((u32)f2bf(acc[m][n][1]) << 16);
        u32 hi = (u32)f2bf(acc[m][n][2]) | ((u32)f2bf(acc[m][n][3]) << 16);
        uint2 pk; pk.x = lo; pk.y = hi;
        *(uint2*)((u16*)Cp + (size_t)c * M + r0) = pk;
      } else {
#pragma unroll
        for (int j = 0; j < 4; ++j) {
          int r = row0 + wr * 64 + m * 16 + q4 * 4 + j;
          int c = col0 + wc * 64 + n * 16 + c15;
          if constexpr (BF16OUT)
            ((u16*)Cp)[(size_t)r * N + c] = f2bf(acc[m][n][j]);
          else
            ((float*)Cp)[(size_t)r * N + c] = acc[m][n][j];
        }
      }
    }
  }
}

// ---------------- causal flash attention, bf16 MFMA, online softmax ----------------
// grid (32, NH): block handles q-tiles (63-bx) and (bx) -> exactly 65 kv-iters each.
// K [S][E] staged to Ks[key][256]; V pre-transposed global [E][S] staged to Vt[d][64].
// Staging goes global->regs (issued a tile early) -> LDS (T14 async split).
__global__ __launch_bounds__(256, 2) void attn_kernel(const u16* __restrict__ Q, const u16* __restrict__ K,
                                                      const u16* __restrict__ Vg, u16* __restrict__ O) {
  __shared__ u16 Ks[64 * 256];   // phys chunk16 = logical ^ (key&7)
  __shared__ u16 Vt[256 * 64];   // phys chunk16 = logical ^ (d&7)
  __shared__ u16 Ps[4][16 * 72];

  const int tid = threadIdx.x, w = tid >> 6, lane = tid & 63;
  const int c15 = lane & 15, q4 = lane >> 4;
  const int h = blockIdx.y;

  const u16* kb = K + h * HD;
  const u16* vb = Vg + (size_t)(h * HD) * SEQL;

  int4 kreg[8], vreg[8];

  for (int pass = 0; pass < 2; ++pass) {
    const int qt = (pass == 0) ? (63 - (int)blockIdx.x) : (int)blockIdx.x;
    const int qbase = qt * 64;

    // Q fragments
    bf16x8 qf[8];
    {
      const u16* qp = Q + (size_t)(qbase + w * 16 + c15) * E + h * HD + q4 * 8;
#pragma unroll
      for (int kc = 0; kc < 8; ++kc) qf[kc] = *(const bf16x8*)(qp + kc * 32);
    }

    f32x4 oacc[16];
#pragma unroll
    for (int i = 0; i < 16; ++i) oacc[i] = f32x4{0.f, 0.f, 0.f, 0.f};
    float mrow[4] = {-3e38f, -3e38f, -3e38f, -3e38f};
    float lrow[4] = {0.f, 0.f, 0.f, 0.f};

    // prologue: load tile 0 into regs
#pragma unroll
    for (int i = 0; i < 8; ++i) {
      int f = i * 256 + tid; int key = f >> 5, c = f & 31;
      kreg[i] = *(const int4*)(kb + (size_t)key * E + c * 8);
    }
#pragma unroll
    for (int i = 0; i < 8; ++i) {
      int f = i * 256 + tid; int d = f >> 3, c = f & 7;
      vreg[i] = *(const int4*)(vb + (size_t)d * SEQL + c * 8);
    }

    for (int t = 0; t <= qt; ++t) {
      const int kvbase = t * 64;
      __syncthreads();   // all waves done reading LDS of prev tile
      // regs -> LDS (compiler inserts vmcnt waits on reg deps)
#pragma unroll
      for (int i = 0; i < 8; ++i) {
        int f = i * 256 + tid; int key = f >> 5, c = f & 31;
        *(int4*)&Ks[key * 256 + ((c ^ (key & 7)) << 3)] = kreg[i];
      }
#pragma unroll
      for (int i = 0; i < 8; ++i) {
        int f = i * 256 + tid; int d = f >> 3, c = f & 7;
        *(int4*)&Vt[(d << 6) + ((c ^ (d & 7)) << 3)] = vreg[i];
      }
      __syncthreads();
      // prefetch next tile into regs; latency hides under compute below
      if (t < qt) {
        const int nb = kvbase + 64;
#pragma unroll
        for (int i = 0; i < 8; ++i) {
          int f = i * 256 + tid; int key = f >> 5, c = f & 31;
          kreg[i] = *(const int4*)(kb + (size_t)(nb + key) * E + c * 8);
        }
#pragma unroll
        for (int i = 0; i < 8; ++i) {
          int f = i * 256 + tid; int d = f >> 3, c = f & 7;
          vreg[i] = *(const int4*)(vb + (size_t)d * SEQL + nb + c * 8);
        }
      }

      // ---- QK^T : S[q16][key64] ----
      f32x4 sacc[4];
#pragma unroll
      for (int n = 0; n < 4; ++n) sacc[n] = f32x4{0.f, 0.f, 0.f, 0.f};
#pragma unroll
      for (int kk = 0; kk < 8; ++kk) {
#pragma unroll
        for (int n = 0; n < 4; ++n) {
          int key = n * 16 + c15;
          int pg = (kk * 4 + q4) ^ (key & 7);
          bf16x8 kf = *(const bf16x8*)&Ks[key * 256 + pg * 8];
          sacc[n] = __builtin_amdgcn_mfma_f32_16x16x32_bf16(qf[kk], kf, sacc[n], 0, 0, 0);
        }
      }

      // ---- scale + causal mask (diagonal tile only) ----
      const bool diag = (t == qt);
#pragma unroll
      for (int n = 0; n < 4; ++n) {
#pragma unroll
        for (int j = 0; j < 4; ++j) {
          float s = sacc[n][j] * 0.0625f;
          if (diag) {
            int key = kvbase + n * 16 + c15;
            int qr = qbase + w * 16 + q4 * 4 + j;
            if (key > qr) s = -3e38f;
          }
          sacc[n][j] = s;
        }
      }

      // ---- online softmax ----
      float rmax[4];
#pragma unroll
      for (int j = 0; j < 4; ++j)
        rmax[j] = fmaxf(fmaxf(sacc[0][j], sacc[1][j]), fmaxf(sacc[2][j], sacc[3][j]));
#pragma unroll
      for (int off = 1; off < 16; off <<= 1)
#pragma unroll
        for (int j = 0; j < 4; ++j) rmax[j] = fmaxf(rmax[j], __shfl_xor(rmax[j], off, 64));

      float mnew[4], scl[4], psum[4];
#pragma unroll
      for (int j = 0; j < 4; ++j) {
        mnew[j] = fmaxf(mrow[j], rmax[j]);
        scl[j] = __expf(mrow[j] - mnew[j]);
        mrow[j] = mnew[j];
        psum[j] = 0.f;
      }

      u16* Pw = &Ps[w][0];
#pragma unroll
      for (int n = 0; n < 4; ++n) {
#pragma unroll
        for (int j = 0; j < 4; ++j) {
          float p = __expf(sacc[n][j] - mnew[j]);
          psum[j] += p;
          Pw[(q4 * 4 + j) * 72 + n * 16 + c15] = f2bf(p);
        }
      }
#pragma unroll
      for (int off = 1; off < 16; off <<= 1)
#pragma unroll
        for (int j = 0; j < 4; ++j) psum[j] += __shfl_xor(psum[j], off, 64);
#pragma unroll
      for (int j = 0; j < 4; ++j) lrow[j] = lrow[j] * scl[j] + psum[j];
#pragma unroll
      for (int i = 0; i < 16; ++i)
#pragma unroll
        for (int j = 0; j < 4; ++j) oacc[i][j] *= scl[j];

      // wave-internal P write->read ordering
      asm volatile("s_waitcnt lgkmcnt(0)" ::: "memory");
      __builtin_amdgcn_sched_barrier(0);

      // ---- PV : O[q16][d256] += P[q16][key64] * V^T ----
      bf16x8 pf[2];
#pragma unroll
      for (int kkp = 0; kkp < 2; ++kkp)
        pf[kkp] = *(const bf16x8*)(Pw + c15 * 72 + kkp * 32 + q4 * 8);
#pragma unroll
      for (int kkp = 0; kkp < 2; ++kkp) {
#pragma unroll
        for (int n = 0; n < 16; ++n) {
          int d = n * 16 + c15;
          int pg = (kkp * 4 + q4) ^ (d & 7);
          bf16x8 vf = *(const bf16x8*)&Vt[(d << 6) + pg * 8];
          oacc[n] = __builtin_amdgcn_mfma_f32_16x16x32_bf16(pf[kkp], vf, oacc[n], 0, 0, 0);
        }
      }
    }

    // ---- finalize this q-tile ----
#pragma unroll
    for (int n = 0; n < 16; ++n) {
#pragma unroll
      for (int j = 0; j < 4; ++j) {
        int r = qbase + w * 16 + q4 * 4 + j;
        int c = h * HD + n * 16 + c15;
        O[(size_t)r * E + c] = f2bf(oacc[n][j] / lrow[j]);
      }
    }
  }
}

// ---------------- launch ----------------
extern "C" void kernel_launch(void* const* d_in, const int* in_sizes, int n_in,
                              void* d_out, int out_size, void* d_ws, size_t ws_size,
                              hipStream_t stream) {
  const float* hs = (const float*)d_in[0];
  const float* wq = (const float*)d_in[1];
  const float* wk = (const float*)d_in[2];
  const float* wv = (const float*)d_in[3];
  const float* wo = (const float*)d_in[4];
  float* out = (float*)d_out;

  const size_t SZ = (size_t)SEQL * E;
  const size_t SZb = SZ * 2;
  char* ws = (char*)d_ws;
  u16* hs_bf = (u16*)(ws);
  u16* wbuf  = (u16*)(ws + SZb);
  u16* q_bf  = (u16*)(ws + 2 * SZb);
  u16* k_bf  = (u16*)(ws + 3 * SZb);
  u16* vt_g  = (u16*)(ws + 4 * SZb);   // V^T, [E][SEQL]
  u16* ao_bf = (u16*)(ws + 5 * SZb);
  float2* sc = (float2*)(ws + 6 * SZb);

  const int n4 = (int)(SZ / 4);
  const int cblocks = (n4 + 255) / 256;

  cast_kernel<<<cblocks, 256, 0, stream>>>((const float4*)hs, (ushort4*)hs_bf, n4);
  sincos_kernel<<<(SEQL * 32 + 255) / 256, 256, 0, stream>>>(sc);

  cast_kernel<<<cblocks, 256, 0, stream>>>((const float4*)wq, (ushort4*)wbuf, n4);
  gemm_bt<true, false><<<1024, 256, 0, stream>>>(hs_bf, wbuf, q_bf, 4096, 4096, 4096);
  cast_kernel<<<cblocks, 256, 0, stream>>>((const float4*)wk, (ushort4*)wbuf, n4);
  gemm_bt<true, false><<<1024, 256, 0, stream>>>(hs_bf, wbuf, k_bf, 4096, 4096, 4096);
  cast_kernel<<<cblocks, 256, 0, stream>>>((const float4*)wv, (ushort4*)wbuf, n4);
  gemm_bt<true, true><<<1024, 256, 0, stream>>>(hs_bf, wbuf, vt_g, 4096, 4096, 4096);

  rope_kernel<<<(SEQL * NH * 32 + 255) / 256, 256, 0, stream>>>(q_bf, k_bf, sc);

  attn_kernel<<<dim3(32, 16), 256, 0, stream>>>(q_bf, k_bf, vt_g, ao_bf);

  cast_kernel<<<cblocks, 256, 0, stream>>>((const float4*)wo, (ushort4*)wbuf, n4);
  gemm_bt<false, false><<<1024, 256, 0, stream>>>(ao_bf, wbuf, out, 4096, 4096, 4096);
}